// Round 2
// baseline (121.979 us; speedup 1.0000x reference)
//
#include <hip/hip_runtime.h>

// CAPE skip-gram NS loss: gather + dot products.
// 16 lanes per batch element; each lane owns a float4 (16B) slice of the
// D=64 row, so one wave-level load instruction fetches 4 full 256B rows.
// R2: issue ALL 12 row loads for a batch element before any reduction,
// so the loads overlap (was VGPR=16 -> ~2 loads in flight -> latency-bound).

__global__ __launch_bounds__(256) void CAPE_43525198578167_kernel(
    const float* __restrict__ emb_in,    // [POI, 64]
    const float* __restrict__ emb_out,   // [POI, 64]
    const int*   __restrict__ target,    // [B]
    const int*   __restrict__ context,   // [B]
    const int*   __restrict__ negs,      // [B, NS]
    float* __restrict__ target_loss,     // [B]
    float* __restrict__ neg_loss,        // [B, NS]
    int B)
{
    const int lane16  = threadIdx.x & 15;
    const int group   = (int)((blockIdx.x * blockDim.x + threadIdx.x) >> 4);
    const int ngroups = (int)((gridDim.x * blockDim.x) >> 4);

    const float4* ein4  = reinterpret_cast<const float4*>(emb_in);
    const float4* eout4 = reinterpret_cast<const float4*>(emb_out);

    for (int b = group; b < B; b += ngroups) {
        // ---- issue all index loads first ----
        const int t = target[b];
        const int c = context[b];
        int idx[10];
        #pragma unroll
        for (int n = 0; n < 10; ++n) idx[n] = negs[b * 10 + n];

        // ---- issue all 12 row loads before any use ----
        const float4 ei = ein4[(size_t)t * 16 + lane16];
        const float4 eo = eout4[(size_t)c * 16 + lane16];
        float4 v[10];
        #pragma unroll
        for (int n = 0; n < 10; ++n)
            v[n] = eout4[(size_t)idx[n] * 16 + lane16];

        // ---- now consume ----
        float p = ei.x * eo.x + ei.y * eo.y + ei.z * eo.z + ei.w * eo.w;
        p += __shfl_xor(p, 1);
        p += __shfl_xor(p, 2);
        p += __shfl_xor(p, 4);
        p += __shfl_xor(p, 8);
        if (lane16 == 0) target_loss[b] = p;

        float q[10];
        #pragma unroll
        for (int n = 0; n < 10; ++n) {
            float s = ei.x * v[n].x + ei.y * v[n].y + ei.z * v[n].z + ei.w * v[n].w;
            s += __shfl_xor(s, 1);
            s += __shfl_xor(s, 2);
            s += __shfl_xor(s, 4);
            s += __shfl_xor(s, 8);
            q[n] = s;
        }
        #pragma unroll
        for (int n = 0; n < 10; ++n)
            if (lane16 == n) neg_loss[b * 10 + n] = -q[n];   // e_neg = -emb_out[idx]
    }
}

extern "C" void kernel_launch(void* const* d_in, const int* in_sizes, int n_in,
                              void* d_out, int out_size, void* d_ws, size_t ws_size,
                              hipStream_t stream) {
    const float* emb_in  = (const float*)d_in[0];
    const float* emb_out = (const float*)d_in[1];
    const int*   target  = (const int*)d_in[2];
    const int*   context = (const int*)d_in[3];
    const int*   negs    = (const int*)d_in[4];

    const int B = in_sizes[2];           // 262144

    float* out = (float*)d_out;
    float* target_loss = out;            // [B]
    float* neg_loss    = out + B;        // [B, NS]

    const int block = 256;
    const int grid  = 2048;              // 8192 waves = 32 waves/CU at <=64 VGPR
    CAPE_43525198578167_kernel<<<grid, block, 0, stream>>>(
        emb_in, emb_out, target, context, negs, target_loss, neg_loss, B);
}

// Round 3
// 117.123 us; speedup vs baseline: 1.0415x; 1.0415x over previous
//
#include <hip/hip_runtime.h>

// CAPE skip-gram NS loss: gather + dot products, memory-latency/BW-bound.
// 16 lanes per batch element, float4 per lane -> one load instr = 4 full rows.
// R3: backfill launch — 16384 short blocks (1 element per group, no loop).
// R2's exact-fill grid-stride left half the wave slots dead (occ 89%->49%);
// short blocks let the CP refill slots as waves retire at random times.

__global__ __launch_bounds__(256) void CAPE_43525198578167_kernel(
    const float* __restrict__ emb_in,    // [POI, 64]
    const float* __restrict__ emb_out,   // [POI, 64]
    const int*   __restrict__ target,    // [B]
    const int*   __restrict__ context,   // [B]
    const int*   __restrict__ negs,      // [B, NS]
    float* __restrict__ target_loss,     // [B]
    float* __restrict__ neg_loss,        // [B, NS]
    int B)
{
    const int lane16 = threadIdx.x & 15;
    const int b = (int)(blockIdx.x * 16 + (threadIdx.x >> 4));
    if (b >= B) return;

    const float4* ein4  = reinterpret_cast<const float4*>(emb_in);
    const float4* eout4 = reinterpret_cast<const float4*>(emb_out);

    // ---- issue all index loads ----
    const int t = target[b];
    const int c = context[b];
    int idx[10];
    #pragma unroll
    for (int n = 0; n < 10; ++n) idx[n] = negs[b * 10 + n];

    // ---- issue all 12 row loads before any use ----
    const float4 ei = ein4[(size_t)t * 16 + lane16];
    const float4 eo = eout4[(size_t)c * 16 + lane16];
    float4 v[10];
    #pragma unroll
    for (int n = 0; n < 10; ++n)
        v[n] = eout4[(size_t)idx[n] * 16 + lane16];

    // ---- consume ----
    float p = ei.x * eo.x + ei.y * eo.y + ei.z * eo.z + ei.w * eo.w;
    p += __shfl_xor(p, 1);
    p += __shfl_xor(p, 2);
    p += __shfl_xor(p, 4);
    p += __shfl_xor(p, 8);
    if (lane16 == 0) target_loss[b] = p;

    float myq = 0.0f;
    #pragma unroll
    for (int n = 0; n < 10; ++n) {
        float s = ei.x * v[n].x + ei.y * v[n].y + ei.z * v[n].z + ei.w * v[n].w;
        s += __shfl_xor(s, 1);
        s += __shfl_xor(s, 2);
        s += __shfl_xor(s, 4);
        s += __shfl_xor(s, 8);
        if (lane16 == n) myq = s;        // lane n keeps result for sample n
    }
    if (lane16 < 10) neg_loss[b * 10 + lane16] = -myq;   // one coalesced store
}

extern "C" void kernel_launch(void* const* d_in, const int* in_sizes, int n_in,
                              void* d_out, int out_size, void* d_ws, size_t ws_size,
                              hipStream_t stream) {
    const float* emb_in  = (const float*)d_in[0];
    const float* emb_out = (const float*)d_in[1];
    const int*   target  = (const int*)d_in[2];
    const int*   context = (const int*)d_in[3];
    const int*   negs    = (const int*)d_in[4];

    const int B = in_sizes[2];           // 262144

    float* out = (float*)d_out;
    float* target_loss = out;            // [B]
    float* neg_loss    = out + B;        // [B, NS]

    const int block = 256;               // 16 elements per block
    const int grid  = (B + 15) / 16;     // 16384 blocks -> deep backfill queue
    CAPE_43525198578167_kernel<<<grid, block, 0, stream>>>(
        emb_in, emb_out, target, context, negs, target_loss, neg_loss, B);
}